// Round 1
// baseline (422.227 us; speedup 1.0000x reference)
//
#include <hip/hip_runtime.h>

typedef short  short8   __attribute__((ext_vector_type(8)));
typedef float  floatx4  __attribute__((ext_vector_type(4)));
typedef unsigned short ushortx4 __attribute__((ext_vector_type(4)));

#define LOG2E_X2 2.8853900817779268f

__device__ __forceinline__ float tanh_fast(float a) {
    // tanh(a) = 1 - 2/(exp(2a)+1), exp(2a) = 2^(a*2*log2(e))
    float e = __builtin_amdgcn_exp2f(a * LOG2E_X2);
    return 1.0f - 2.0f * __builtin_amdgcn_rcpf(1.0f + e);
}

__device__ __forceinline__ unsigned short bf16rne(float f) {
    unsigned u = __float_as_uint(f);
    u += 0x7FFFu + ((u >> 16) & 1u);   // round-to-nearest-even
    return (unsigned short)(u >> 16);
}

// Grid: 512 blocks x 256 threads. Each block owns 64 ODE rows for the whole
// trajectory (8 blocks x 2 RK4 steps x 4 substeps = 64 MLP evals).
// Transposed GEMMs: hT = W1T(256x96) @ XT(96x64), outT = W2T(64x256) @ hT(256x64)
// so MFMA C-layout gives each lane 4 CONSECUTIVE hidden/d columns -> packed b64 LDS writes
// and register-resident RK4 state aligned with MFMA output ownership.
__global__ __launch_bounds__(256, 2) void ode_mfma(
    const float* __restrict__ s_in,  const float* __restrict__ t_in,
    const float* __restrict__ phi_in,const float* __restrict__ bfr_in,
    const float* __restrict__ w1_in, const float* __restrict__ b1_in,
    const float* __restrict__ w2_in, const float* __restrict__ b2_in,
    float* __restrict__ out)
{
    const int tid  = threadIdx.x;
    const int wv   = tid >> 6;         // wave 0..3
    const int lane = tid & 63;
    const int l15  = lane & 15;
    const int q    = lane >> 4;        // quad 0..3
    const int wg   = blockIdx.x;       // 0..511
    const int sb   = wg >> 5;          // (s*8+b) 0..15
    const int n0   = (wg & 31) << 6;   // node base within (s,b)
    const int rowg0 = sb * 2048 + n0;  // global row base (row = sb*N + n)

    // LDS: X||Phi tile (96 cols used, stride 104 to spread banks), h tile (stride 264)
    __shared__ __align__(16) unsigned short Atile[64][104];
    __shared__ __align__(16) unsigned short Hs[64][264];
    __shared__ __align__(16) float b1s[256];
    __shared__ float dls[8];

    const int d0 = wv * 16 + q * 4;    // this lane's 4 consecutive d columns

    // ---- persistent register fragments -------------------------------------
    // W1 A-frags: wave wv owns hidden cols [wv*64, wv*64+64): 4 ht-tiles x 3 K-steps
    short8 w1f[4][3];
#pragma unroll
    for (int ht = 0; ht < 4; ++ht)
#pragma unroll
        for (int kk = 0; kk < 3; ++kk) {
            short8 f;
#pragma unroll
            for (int j = 0; j < 8; ++j) {
                int k = kk * 32 + q * 8 + j;                 // feature index
                int hc = (wv * 4 + ht) * 16 + l15;           // hidden index (A: m=l15)
                f[j] = (short)bf16rne(w1_in[k * 256 + hc]);
            }
            w1f[ht][kk] = f;
        }
    // W2 A-frags: wave wv owns d cols [wv*16, wv*16+16): 8 K-steps
    short8 w2f[8];
#pragma unroll
    for (int kk = 0; kk < 8; ++kk) {
        short8 f;
#pragma unroll
        for (int j = 0; j < 8; ++j) {
            int k = kk * 32 + q * 8 + j;                     // hidden index
            f[j] = (short)bf16rne(w2_in[k * 64 + wv * 16 + l15]);
        }
        w2f[kk] = f;
    }

    const floatx4 b2v = *(const floatx4*)(b2_in + d0);

    // RK4 state: lane owns (row = rt*16+l15, d = d0..d0+3), rt = 0..3
    floatx4 xv[4], bfrc[4], kacc[4];
#pragma unroll
    for (int rt = 0; rt < 4; ++rt) {
        int rg = rowg0 + rt * 16 + l15;
        xv[rt]   = *(const floatx4*)(s_in   + rg * 64 + d0);
        bfrc[rt] = *(const floatx4*)(bfr_in + rg * 64 + d0);
        ushortx4 px;
#pragma unroll
        for (int r = 0; r < 4; ++r) px[r] = bf16rne(xv[rt][r]);
        *(ushortx4*)&Atile[rt * 16 + l15][d0] = px;
    }
    // Phi -> Atile cols 64..95 (64 rows x 8 float4-chunks = 512 chunks)
#pragma unroll
    for (int it = 0; it < 2; ++it) {
        int c2 = tid * 2 + it;           // 0..511
        int row = c2 >> 3, cc = c2 & 7;
        floatx4 p = *(const floatx4*)(phi_in + (rowg0 + row) * 32 + cc * 4);
        ushortx4 px;
#pragma unroll
        for (int r = 0; r < 4; ++r) px[r] = bf16rne(p[r]);
        *(ushortx4*)&Atile[row][64 + cc * 4] = px;
    }
    if (tid < 64) *(floatx4*)&b1s[tid * 4] = *(const floatx4*)(b1_in + tid * 4);
    if (tid < 8)  dls[tid] = t_in[sb * 9 + tid + 1] - t_in[sb * 9 + tid];

    __syncthreads();

    const floatx4 fzero = {0.f, 0.f, 0.f, 0.f};

#pragma unroll 1
    for (int blk = 0; blk < 8; ++blk) {
        const float dlt = dls[blk];
#pragma unroll 1
        for (int stp = 0; stp < 2; ++stp) {
#pragma unroll 1
            for (int sub = 0; sub < 4; ++sub) {
                __syncthreads();   // A-tile writes visible to all waves

                // ---- GEMM1: hT = W1T @ XT, acc init = b1 ----
                floatx4 acc1[4][4];
#pragma unroll
                for (int ht = 0; ht < 4; ++ht) {
                    floatx4 bb = *(const floatx4*)&b1s[(wv * 4 + ht) * 16 + q * 4];
#pragma unroll
                    for (int rt = 0; rt < 4; ++rt) acc1[ht][rt] = bb;
                }
#pragma unroll
                for (int kk = 0; kk < 3; ++kk) {
                    short8 xb[4];
#pragma unroll
                    for (int rt = 0; rt < 4; ++rt)
                        xb[rt] = *(const short8*)&Atile[rt * 16 + l15][kk * 32 + q * 8];
#pragma unroll
                    for (int ht = 0; ht < 4; ++ht)
#pragma unroll
                        for (int rt = 0; rt < 4; ++rt)
                            acc1[ht][rt] = __builtin_amdgcn_mfma_f32_16x16x32_bf16(
                                w1f[ht][kk], xb[rt], acc1[ht][rt], 0, 0, 0);
                }
                // ---- tanh + pack to Hs (4 consecutive hidden per lane -> b64) ----
#pragma unroll
                for (int ht = 0; ht < 4; ++ht)
#pragma unroll
                    for (int rt = 0; rt < 4; ++rt) {
                        ushortx4 hp;
#pragma unroll
                        for (int r = 0; r < 4; ++r)
                            hp[r] = bf16rne(tanh_fast(acc1[ht][rt][r]));
                        *(ushortx4*)&Hs[rt * 16 + l15][(wv * 4 + ht) * 16 + q * 4] = hp;
                    }
                __syncthreads();   // Hs visible; Atile reads done -> safe to rewrite

                // ---- GEMM2: outT = W2T @ hT ----
                floatx4 acc2[4];
#pragma unroll
                for (int rt = 0; rt < 4; ++rt) acc2[rt] = fzero;
#pragma unroll
                for (int kk = 0; kk < 8; ++kk)
#pragma unroll
                    for (int rt = 0; rt < 4; ++rt) {
                        short8 hb = *(const short8*)&Hs[rt * 16 + l15][kk * 32 + q * 8];
                        acc2[rt] = __builtin_amdgcn_mfma_f32_16x16x32_bf16(
                            w2f[kk], hb, acc2[rt], 0, 0, 0);
                    }
                // ---- RK4 epilogue (registers) + write next eval point to Atile ----
#pragma unroll
                for (int rt = 0; rt < 4; ++rt) {
                    floatx4 kv = (acc2[rt] + b2v + bfrc[rt]) * dlt;
                    floatx4 xe;
                    if (sub == 0)      { kacc[rt] = kv;            xe = xv[rt] + 0.25f * kv; }
                    else if (sub == 1) { kacc[rt] += 2.0f * kv;    xe = xv[rt] + 0.25f * kv; }
                    else if (sub == 2) { kacc[rt] += 2.0f * kv;    xe = xv[rt] + 0.5f  * kv; }
                    else               { xv[rt] += (kacc[rt] + kv) * (1.0f / 12.0f); xe = xv[rt]; }
                    ushortx4 px;
#pragma unroll
                    for (int r = 0; r < 4; ++r) px[r] = bf16rne(xe[r]);
                    *(ushortx4*)&Atile[rt * 16 + l15][d0] = px;
                }
            }
        }
        // ---- emit x after this block step: out[(sb*8+blk)*N + n][d] ----
        const int ob = (sb * 8 + blk) * 2048;
#pragma unroll
        for (int rt = 0; rt < 4; ++rt)
            *(floatx4*)(out + (size_t)(ob + n0 + rt * 16 + l15) * 64 + d0) = xv[rt];
    }
}

extern "C" void kernel_launch(void* const* d_in, const int* in_sizes, int n_in,
                              void* d_out, int out_size, void* d_ws, size_t ws_size,
                              hipStream_t stream) {
    const float* s_in  = (const float*)d_in[0];
    const float* t_in  = (const float*)d_in[1];
    const float* phi   = (const float*)d_in[2];
    const float* bfr   = (const float*)d_in[3];
    const float* w1    = (const float*)d_in[4];
    const float* b1    = (const float*)d_in[5];
    const float* w2    = (const float*)d_in[6];
    const float* b2    = (const float*)d_in[7];
    ode_mfma<<<512, 256, 0, stream>>>(s_in, t_in, phi, bfr, w1, b1, w2, b2, (float*)d_out);
}